// Round 1
// baseline (501.227 us; speedup 1.0000x reference)
//
#include <hip/hip_runtime.h>

// Problem constants (from reference):
//   T=2000 tags, V=20000 videos, D=768, E_POS=E_NEG=100000
// Outputs (fp32, concatenated flat):
//   cls_score [V, T]  (scatter-add of edge dot products)
//   labels    [V, T]  (scatter-add of 1.0 at positive edges)

#define T_DIM 2000
#define V_DIM 20000
#define D_DIM 768
#define EPOS  100000
#define ENEG  100000
#define ETOT  (EPOS + ENEG)

// One wave (64 lanes) per edge. D=768 -> 192 float4 per row -> 3 float4/lane.
__global__ __launch_bounds__(256) void edge_dot_scatter(
    const float* __restrict__ h_tag,
    const float* __restrict__ h_video,
    const int*   __restrict__ pos_src,
    const int*   __restrict__ pos_dst,
    const int*   __restrict__ neg_src,
    const int*   __restrict__ neg_dst,
    float*       __restrict__ cls_score,
    float*       __restrict__ labels)
{
    const int wave = threadIdx.x >> 6;          // 4 waves per block
    const int lane = threadIdx.x & 63;
    const int edge = blockIdx.x * 4 + wave;
    if (edge >= ETOT) return;

    int src, dst;
    if (edge < EPOS) {
        src = pos_src[edge];
        dst = pos_dst[edge];
    } else {
        src = neg_src[edge - EPOS];
        dst = neg_dst[edge - EPOS];
    }

    const float4* a = (const float4*)(h_tag   + (size_t)src * D_DIM);
    const float4* b = (const float4*)(h_video + (size_t)dst * D_DIM);

    float acc = 0.0f;
#pragma unroll
    for (int i = 0; i < 3; ++i) {
        const float4 av = a[lane + i * 64];
        const float4 bv = b[lane + i * 64];
        acc += av.x * bv.x + av.y * bv.y + av.z * bv.z + av.w * bv.w;
    }

    // 64-lane butterfly reduce
#pragma unroll
    for (int off = 32; off >= 1; off >>= 1)
        acc += __shfl_down(acc, off, 64);

    if (lane == 0) {
        const size_t idx = (size_t)dst * T_DIM + src;
        atomicAdd(&cls_score[idx], acc);
        if (edge < EPOS)
            atomicAdd(&labels[idx], 1.0f);
    }
}

extern "C" void kernel_launch(void* const* d_in, const int* in_sizes, int n_in,
                              void* d_out, int out_size, void* d_ws, size_t ws_size,
                              hipStream_t stream)
{
    const float* h_tag   = (const float*)d_in[0];
    const float* h_video = (const float*)d_in[1];
    const int*   pos_src = (const int*)d_in[2];
    const int*   pos_dst = (const int*)d_in[3];
    const int*   neg_src = (const int*)d_in[4];
    const int*   neg_dst = (const int*)d_in[5];

    float* cls_score = (float*)d_out;                          // [V, T]
    float* labels    = (float*)d_out + (size_t)V_DIM * T_DIM;  // [V, T]

    // Zero both outputs (harness re-poisons d_out to 0xAA before every call).
    hipMemsetAsync(d_out, 0, (size_t)out_size * sizeof(float), stream);

    const int blocks = (ETOT + 3) / 4;  // 4 edges (waves) per 256-thread block
    edge_dot_scatter<<<blocks, 256, 0, stream>>>(
        h_tag, h_video, pos_src, pos_dst, neg_src, neg_dst, cls_score, labels);
}